// Round 18
// baseline (85.431 us; speedup 1.0000x reference)
//
#include <hip/hip_runtime.h>
#include <hip/hip_bf16.h>
#include <string.h>

typedef __attribute__((ext_vector_type(8))) short bf16x8;
typedef __attribute__((ext_vector_type(4))) short bf16x4;
typedef __attribute__((ext_vector_type(4))) float f32x4;
typedef __attribute__((ext_vector_type(4))) int i32x4;
typedef __attribute__((ext_vector_type(2))) int i32x2;

#define DEV __device__ __forceinline__
#define WIN_ 1024

DEV short f2bf(float f) {
  __hip_bfloat16 h = __float2bfloat16(f);
  short s; __builtin_memcpy(&s, &h, 2); return s;
}
DEV float bf2f(short s) {
  union { unsigned u; float f; } a; a.u = ((unsigned)(unsigned short)s) << 16;
  return a.f;
}
DEV unsigned pkbf2(float a, float b) {     // packed f32x2 -> bf16x2 (RNE), compiler-emitted
  __hip_bfloat162 h = __float22bfloat162_rn(make_float2(a, b));
  unsigned u; __builtin_memcpy(&u, &h, 4); return u;
}
DEV float fexp2(float x) {
#if __has_builtin(__builtin_amdgcn_exp2f)
  return __builtin_amdgcn_exp2f(x);
#else
  return exp2f(x);
#endif
}

DEV f32x4 mfma16(bf16x4 a, bf16x4 b, f32x4 c) {
#if __has_builtin(__builtin_amdgcn_mfma_f32_16x16x16bf16_1k)
  return __builtin_amdgcn_mfma_f32_16x16x16bf16_1k(a, b, c, 0, 0, 0);
#else
  asm volatile("s_nop 1\n\tv_mfma_f32_16x16x16_bf16 %0, %1, %2, %0\n\ts_nop 7\n\ts_nop 7"
               : "+v"(c) : "v"(a), "v"(b));
  return c;
#endif
}

DEV void gload16(const short* g, short* l) {
  __builtin_amdgcn_global_load_lds((const __attribute__((address_space(1))) unsigned int*)g,
                                   (__attribute__((address_space(3))) unsigned int*)l,
                                   16, 0, 0);
}

// ---------- fused prep: x->bf16 cast (8 floats/thread) + 4 weight transposes ----------
__global__ __launch_bounds__(256) void k_prep(const float* __restrict__ x,
    const float* __restrict__ Wq, const float* __restrict__ Wk, const float* __restrict__ Wv,
    const float* __restrict__ Wo, short* __restrict__ xb, short* __restrict__ WbT,
    short* __restrict__ WoT) {
  const int bid = blockIdx.x;
  if (bid < 2048) {                       // cvt: 4096x1024 f32 -> bf16, 8 elems/thread
    size_t i = ((size_t)bid * 256 + threadIdx.x) * 8;
    f32x4 v0 = *(const f32x4*)(x + i);
    f32x4 v1 = *(const f32x4*)(x + i + 4);
    i32x4 o = {(int)pkbf2(v0[0], v0[1]), (int)pkbf2(v0[2], v0[3]),
               (int)pkbf2(v1[0], v1[1]), (int)pkbf2(v1[2], v1[3])};
    *(i32x4*)(xb + i) = o;
    return;
  }
  int t = bid - 2048;
  const float* src; short* dst; int srcld, bx, by;
  if (t < 1024)      { src = Wq; dst = WbT;                        srcld = 1024; bx = t & 31;          by = t >> 5; }
  else if (t < 1280) { src = Wk; dst = WbT + (size_t)1024 * 1024;  srcld = 256;  bx = (t - 1024) & 7;  by = (t - 1024) >> 3; }
  else if (t < 1536) { src = Wv; dst = WbT + (size_t)1280 * 1024;  srcld = 256;  bx = (t - 1280) & 7;  by = (t - 1280) >> 3; }
  else               { src = Wo; dst = WoT;                        srcld = 1024; bx = (t - 1536) & 31; by = (t - 1536) >> 5; }
  __shared__ float tile[32][33];
  const int n0 = bx * 32, k0 = by * 32;
  const int tx = threadIdx.x & 31, ty = threadIdx.x >> 5;
#pragma unroll
  for (int i = 0; i < 4; ++i)
    tile[ty * 4 + i][tx] = src[(size_t)(k0 + ty * 4 + i) * srcld + n0 + tx];
  __syncthreads();
#pragma unroll
  for (int i = 0; i < 4; ++i)
    dst[(size_t)(n0 + ty * 4 + i) * 1024 + k0 + tx] = f2bf(tile[tx][ty * 4 + i]);
}

// ======== fused QKV GEMM + RoPE/RMSNorm/gate epilogue ========
// 1D grid (768), XCD-swizzled decode (T1).
__global__ __launch_bounds__(256) void k_gemm_qkv(const short* __restrict__ A, const short* __restrict__ BT,
    const float* __restrict__ x, const float* __restrict__ ve,
    const float* __restrict__ cosp, const float* __restrict__ sinp, const float* __restrict__ Wg,
    short* __restrict__ qh, short* __restrict__ kh, short* __restrict__ vhT) {
  const int K = 1024;
  __shared__ short As[2][8192];   // 128 rows x 64
  __shared__ short Bs[2][4096];   // 64 rows x 64
  const int tid = threadIdx.x;
  const int l = tid & 63, w = tid >> 6;
  const int l15 = l & 15, hi = l >> 4;
  const int bid = blockIdx.x;
  const int wg = (bid & 7) * 96 + (bid >> 3);       // XCD-contiguous remap (768 = 8*96)
  const int bx = wg % 24;
  const int m0 = (wg / 24) * 128, n0 = bx * 64;
  const int srow = tid >> 3;
  const int segsw = 8 * ((tid & 7) ^ (srow & 7));
  const int lo = tid * 8;
  const short* pa = A + (size_t)(m0 + srow) * K + segsw;
  const short* pb = BT + (size_t)(n0 + srow) * K + segsw;
  const int f8 = l15 & 7;

  f32x4 acc[2][4];
#pragma unroll
  for (int i = 0; i < 2; ++i)
#pragma unroll
    for (int j = 0; j < 4; ++j) acc[i][j] = (f32x4){0.f, 0.f, 0.f, 0.f};

  auto stage = [&](int buf, int koff) {
    gload16(pa + koff,          &As[buf][lo]);
    gload16(pa + 32 * K + koff, &As[buf][lo + 2048]);
    gload16(pa + 64 * K + koff, &As[buf][lo + 4096]);
    gload16(pa + 96 * K + koff, &As[buf][lo + 6144]);
    gload16(pb + koff,          &Bs[buf][lo]);
    gload16(pb + 32 * K + koff, &Bs[buf][lo + 2048]);
  };

  stage(0, 0);
  __syncthreads();
  int cur = 0;
  for (int k0 = 0; k0 < K; k0 += 64) {
    if (k0 + 64 < K) stage(cur ^ 1, k0 + 64);
    bf16x8 af[2][2], bfr[4][2];
#pragma unroll
    for (int c = 0; c < 2; ++c) {
      int seg = 8 * ((4 * c + hi) ^ f8);
#pragma unroll
      for (int mi = 0; mi < 2; ++mi)
        af[mi][c] = *(const bf16x8*)&As[cur][(32 * w + 16 * mi + l15) * 64 + seg];
#pragma unroll
      for (int ni = 0; ni < 4; ++ni)
        bfr[ni][c] = *(const bf16x8*)&Bs[cur][(16 * ni + l15) * 64 + seg];
    }
#pragma unroll
    for (int c = 0; c < 2; ++c)
#pragma unroll
      for (int mi = 0; mi < 2; ++mi)
#pragma unroll
        for (int ni = 0; ni < 4; ++ni)
          acc[mi][ni] = __builtin_amdgcn_mfma_f32_16x16x32_bf16(af[mi][c], bfr[ni][c], acc[mi][ni], 0, 0, 0);
    __syncthreads();
    cur ^= 1;
  }

  // ---------------- fused epilogue ----------------
  if (bx < 20) {
    short* dst0 = (bx < 16) ? qh : kh;
#pragma unroll
    for (int mi = 0; mi < 2; ++mi)
#pragma unroll
      for (int r = 0; r < 4; ++r) {
        int bt = m0 + 32 * w + 16 * mi + 4 * hi + r;
        int b = bt >> 11, t = bt & 2047;
        float c0 = cosp[bt * 32 + l15],      s0 = sinp[bt * 32 + l15];
        float c1 = cosp[bt * 32 + 16 + l15], s1 = sinp[bt * 32 + 16 + l15];
        float a0 = acc[mi][0][r], b0 = acc[mi][2][r];
        float a1 = acc[mi][1][r], b1 = acc[mi][3][r];
        float o0 = a0 * c0 + b0 * s0;
        float o2 = b0 * c0 - a0 * s0;
        float o1 = a1 * c1 + b1 * s1;
        float o3 = b1 * c1 - a1 * s1;
        float ss = o0 * o0 + o1 * o1 + o2 * o2 + o3 * o3;
        ss += __shfl_xor(ss, 1); ss += __shfl_xor(ss, 2);
        ss += __shfl_xor(ss, 4); ss += __shfl_xor(ss, 8);
        float rinv = rsqrtf(ss * (1.f / 64.f) + 1e-6f);
        if (bx < 16) rinv *= 0.18033688011112042f;   // 0.125 * log2(e)
        size_t rb = ((size_t)((b * ((bx < 16) ? 16 : 4) + ((bx < 16) ? bx : bx - 16)) * 2048 + t)) * 64;
        dst0[rb + l15]      = f2bf(o0 * rinv);
        dst0[rb + 16 + l15] = f2bf(o1 * rinv);
        dst0[rb + 32 + l15] = f2bf(o2 * rinv);
        dst0[rb + 48 + l15] = f2bf(o3 * rinv);
      }
  } else {
    const int kvh = bx - 20;
#pragma unroll
    for (int mi = 0; mi < 2; ++mi)
#pragma unroll
      for (int r = 0; r < 4; ++r) {
        int bt = m0 + 32 * w + 16 * mi + 4 * hi + r;
        int b = bt >> 11, t = bt & 2047;
        const float* xr = x + (size_t)bt * 1024;
        float z = 0.f;
#pragma unroll
        for (int gg = 0; gg < 32; ++gg) z += xr[gg] * Wg[gg * 4 + kvh];
        float gate = 2.f / (1.f + __expf(-z));
        const float* vep = ve + (size_t)bt * 256 + kvh * 64;
        short* dst = vhT + (size_t)(b * 4 + kvh) * 131072 + t;
#pragma unroll
        for (int ni = 0; ni < 4; ++ni) {
          int d = 16 * ni + l15;
          float vv = acc[mi][ni][r] + gate * vep[d];
          dst[(size_t)d * 2048] = f2bf(vv);
        }
      }
  }
}

// ---------------- bf16 GEMM: C = A(MxK) * BT(NxK)^T ---------------- (gemm2)
// 1D grid (512), XCD-swizzled decode (T1).
template <int LDC, bool F32OUT>
__global__ __launch_bounds__(256) void k_gemm_bt(const short* __restrict__ A, const short* __restrict__ BT,
                                                 void* __restrict__ Cv, int K) {
  __shared__ short As[2][8192];
  __shared__ short Bs[2][4096];
  const int tid = threadIdx.x;
  const int l = tid & 63, w = tid >> 6;
  const int l15 = l & 15, hi = l >> 4;
  const int bid = blockIdx.x;
  const int wg = (bid & 7) * 64 + (bid >> 3);       // XCD-contiguous remap (512 = 8*64)
  const int m0 = (wg >> 4) * 128, n0 = (wg & 15) * 64;
  const int srow = tid >> 3;
  const int segsw = 8 * ((tid & 7) ^ (srow & 7));
  const int lo = tid * 8;
  const short* pa = A + (size_t)(m0 + srow) * K + segsw;
  const short* pb = BT + (size_t)(n0 + srow) * K + segsw;
  const int f8 = l15 & 7;

  f32x4 acc[2][4];
#pragma unroll
  for (int i = 0; i < 2; ++i)
#pragma unroll
    for (int j = 0; j < 4; ++j) acc[i][j] = (f32x4){0.f, 0.f, 0.f, 0.f};

  auto stage = [&](int buf, int koff) {
    gload16(pa + koff,          &As[buf][lo]);
    gload16(pa + 32 * K + koff, &As[buf][lo + 2048]);
    gload16(pa + 64 * K + koff, &As[buf][lo + 4096]);
    gload16(pa + 96 * K + koff, &As[buf][lo + 6144]);
    gload16(pb + koff,          &Bs[buf][lo]);
    gload16(pb + 32 * K + koff, &Bs[buf][lo + 2048]);
  };

  stage(0, 0);
  __syncthreads();
  int cur = 0;
  for (int k0 = 0; k0 < K; k0 += 64) {
    if (k0 + 64 < K) stage(cur ^ 1, k0 + 64);
    bf16x8 af[2][2], bfr[4][2];
#pragma unroll
    for (int c = 0; c < 2; ++c) {
      int seg = 8 * ((4 * c + hi) ^ f8);
#pragma unroll
      for (int mi = 0; mi < 2; ++mi)
        af[mi][c] = *(const bf16x8*)&As[cur][(32 * w + 16 * mi + l15) * 64 + seg];
#pragma unroll
      for (int ni = 0; ni < 4; ++ni)
        bfr[ni][c] = *(const bf16x8*)&Bs[cur][(16 * ni + l15) * 64 + seg];
    }
#pragma unroll
    for (int c = 0; c < 2; ++c)
#pragma unroll
      for (int mi = 0; mi < 2; ++mi)
#pragma unroll
        for (int ni = 0; ni < 4; ++ni)
          acc[mi][ni] = __builtin_amdgcn_mfma_f32_16x16x32_bf16(af[mi][c], bfr[ni][c], acc[mi][ni], 0, 0, 0);
    __syncthreads();
    cur ^= 1;
  }
#pragma unroll
  for (int mi = 0; mi < 2; ++mi)
#pragma unroll
    for (int ni = 0; ni < 4; ++ni)
#pragma unroll
      for (int r = 0; r < 4; ++r) {
        int crow = m0 + 32 * w + 16 * mi + 4 * hi + r;
        int ccol = n0 + 16 * ni + l15;
        if (F32OUT) ((float*)Cv)[(size_t)crow * LDC + ccol] = acc[mi][ni][r];
        else        ((short*)Cv)[(size_t)crow * LDC + ccol] = f2bf(acc[mi][ni][r]);
      }
}

// ---------------- flash attention, sliding-window causal, GQA ----------------
// T15 att[2] double-pipeline with RELATIVE buffer parity (fix of r17 bug:
// tile kt lives in buf[(kt-kt_lo)&1]; absolute kt&1 mis-indexed when kt_lo
// is odd). Iteration computes QK^T(tile kt) [MFMA] while finishing
// softmax+PV of tile kt-1; static-max softmax; lsum via ones-MFMA.
__global__ __launch_bounds__(256) void k_attn(const short* __restrict__ qh, const short* __restrict__ kh,
                                              const short* __restrict__ vhT, short* __restrict__ yb) {
  __shared__ i32x4 lds4[2][1024];   // [buf][ K 8KB | V 8KB ]
  char* base = (char*)lds4;
  const int bid = blockIdx.x;
  const int kq = bid >> 8, low = bid & 255;
  const int h = low & 15, b = (low >> 4) & 1, q0 = low >> 5;
  const int qt = (kq == 0) ? (31 - q0) : (kq == 1) ? (16 + q0) : (kq == 2) ? (15 - q0) : q0;
  const int kvh = h >> 2;
  const int qs = qt * 64;
  const int tid = threadIdx.x;
  const int w = tid >> 6, l = tid & 63, l15 = l & 15, hi = l >> 4;
  const int qi = qs + 16 * w + l15;          // this lane's softmax row
  const int rsw = (l15 & 7) << 4;

  const short* qb = qh + ((size_t)((b * 16 + h) * 2048 + qs + 16 * w + l15)) * 64;
  bf16x8 qf0 = *(const bf16x8*)(qb + 8 * hi);
  bf16x8 qf1 = *(const bf16x8*)(qb + 32 + 8 * hi);

  f32x4 oacc[4];
#pragma unroll
  for (int i = 0; i < 4; ++i) oacc[i] = (f32x4){0.f, 0.f, 0.f, 0.f};
  f32x4 lsacc = (f32x4){0.f, 0.f, 0.f, 0.f};
  const bf16x4 vone = {(short)0x3F80, (short)0x3F80, (short)0x3F80, (short)0x3F80};

  const int kt_lo = (qs >= 1024) ? ((qs - 1024) >> 6) : 0;
  const int kt_hi = qs >> 6;
  const short* kbase = kh + ((size_t)(b * 4 + kvh) * 2048) * 64;
  const short* vbase = vhT + ((size_t)(b * 4 + kvh) * 64) * 2048;

  const int srow = tid >> 3, sseg = tid & 7;
  const int swz = (srow & 7) << 4;
  const int ko = ((srow << 7) + (sseg << 4)) ^ swz;
  const short* kp = kbase + (size_t)(kt_lo * 64 + srow) * 64 + sseg * 8;
  const short* vp = vbase + (size_t)srow * 2048 + kt_lo * 64 + sseg * 8;
  i32x4 rk0, rk1, rv0, rv1;

#define LOADT() do { \
    rk0 = *(const i32x4*)kp; \
    rk1 = *(const i32x4*)(kp + 2048); \
    rv0 = *(const i32x4*)vp; \
    rv1 = *(const i32x4*)(vp + 32 * 2048); \
  } while (0)

#define WRITET(DST) do { \
    char* kd = (DST); \
    *(i32x4*)(kd + ko) = rk0; \
    *(i32x4*)(kd + ko + 4096) = rk1; \
    char* vd = kd + 8192; \
    *(i32x4*)(vd + ko) = rv0; \
    *(i32x4*)(vd + ko + 4096) = rv1; \
  } while (0)

  // QK^T of one tile from kbuf -> s[4]
  auto QKF = [&](char* kbuf, f32x4 (&s)[4]) {
#pragma unroll
    for (int nt = 0; nt < 4; ++nt) s[nt] = (f32x4){0.f, 0.f, 0.f, 0.f};
#pragma unroll
    for (int c = 0; c < 2; ++c) {
      bf16x8 qc = c ? qf1 : qf0;
#pragma unroll
      for (int nt = 0; nt < 4; ++nt) {
        bf16x8 kf = *(const bf16x8*)(kbuf + ((((16 * nt + l15) << 7) + (c << 6) + (hi << 4)) ^ rsw));
        s[nt] = __builtin_amdgcn_mfma_f32_16x16x32_bf16(kf, qc, s[nt], 0, 0, 0);
      }
    }
  };

  // finish tile ktX: mask(edge) -> exp2 -> pack -> lsum-MFMA -> PV (V in vbuf)
  auto FINISH = [&](f32x4 (&s)[4], int ktX, char* kbuf) {
    char* vbuf = kbuf + 8192;
    if (ktX == kt_lo || ktX == kt_hi) {
      const int k0 = ktX * 64;
#pragma unroll
      for (int nt = 0; nt < 4; ++nt)
#pragma unroll
        for (int r = 0; r < 4; ++r) {
          int kj = k0 + 16 * nt + 4 * hi + r;
          if (kj > qi || (qi - kj) > WIN_) s[nt][r] = -1e30f;
        }
    }
#pragma unroll
    for (int nt = 0; nt < 4; ++nt)
#pragma unroll
      for (int r = 0; r < 4; ++r) s[nt][r] = fexp2(s[nt][r]);
    bf16x4 pa[4];
#pragma unroll
    for (int nt = 0; nt < 4; ++nt) {
      i32x2 pk = {(int)pkbf2(s[nt][0], s[nt][1]), (int)pkbf2(s[nt][2], s[nt][3])};
      pa[nt] = __builtin_bit_cast(bf16x4, pk);
    }
#pragma unroll
    for (int nt = 0; nt < 4; ++nt) lsacc = mfma16(vone, pa[nt], lsacc);
#pragma unroll
    for (int dt = 0; dt < 4; ++dt) {
      int rowb = ((16 * dt + l15) << 7) + (hi << 3);
#pragma unroll
      for (int nt = 0; nt < 4; ++nt) {
        i32x2 vv = *(const i32x2*)(vbuf + ((rowb + 32 * nt) ^ rsw));
        oacc[dt] = mfma16(__builtin_bit_cast(bf16x4, vv), pa[nt], oacc[dt]);
      }
    }
  };

  // ---- prologue: tile kt_lo -> buf0 (QK'd); tile kt_lo+1 -> buf1 ----
  LOADT();
  WRITET(base);
  __syncthreads();

  f32x4 sP[4], sC[4];
  QKF(base, sP);
  int ktP = kt_lo;
  int kt = kt_lo;
  if (kt < kt_hi) {
    kp += 4096; vp += 64; LOADT();
    WRITET(base + 16384);            // buf1 unused so far: no barrier needed before write
  }
  __syncthreads();                   // buf1 (tile kt_lo+1) visible

  // ---- pipelined main loop (buffer index = relative parity) ----
  while (kt < kt_hi) {
    ++kt;
    const int par = (kt - kt_lo) & 1;
    char* bufC = base + par * 16384;             // tile kt (K read now, V next iter)
    char* bufP = base + (par ^ 1) * 16384;       // tile kt-1 (V read now, then overwritten)
    if (kt < kt_hi) { kp += 4096; vp += 64; LOADT(); }   // tile kt+1 -> regs
    __builtin_amdgcn_s_setprio(1);
    QKF(bufC, sC);                                // MFMA chain (independent of FINISH)
    __builtin_amdgcn_s_setprio(0);
    FINISH(sP, ktP, bufP);                        // VALU/TRANS + MFMA of previous tile
    __syncthreads();                              // all waves done reading bufP
    if (kt < kt_hi) WRITET(bufP);                 // tile kt+1 into bufP
    __syncthreads();                              // visible for next iteration's QKF
#pragma unroll
    for (int nt = 0; nt < 4; ++nt) sP[nt] = sC[nt];
    ktP = kt;
  }
  // ---- epilogue: finish last tile (relative parity) ----
  FINISH(sP, ktP, base + (((ktP - kt_lo) & 1)) * 16384);

#undef LOADT
#undef WRITET

  // ---- epilogue: lsum already summed across all k by the ones-MFMA ----
  float inv = 1.f / lsacc[0];
  size_t orow = (size_t)(b * 2048 + qs + 16 * w + l15);
#pragma unroll
  for (int dt = 0; dt < 4; ++dt) {
    int col0 = h * 64 + 16 * dt + 4 * hi;
    i32x2 pk = {(int)pkbf2(oacc[dt][0] * inv, oacc[dt][1] * inv),
                (int)pkbf2(oacc[dt][2] * inv, oacc[dt][3] * inv)};
    *(i32x2*)(yb + orow * 1024 + col0) = pk;
  }
}

extern "C" void kernel_launch(void* const* d_in, const int* in_sizes, int n_in,
                              void* d_out, int out_size, void* d_ws, size_t ws_size,
                              hipStream_t stream) {
  const float* x    = (const float*)d_in[0];
  const float* ve   = (const float*)d_in[1];
  const float* cosp = (const float*)d_in[2];
  const float* sinp = (const float*)d_in[3];
  const float* Wq   = (const float*)d_in[4];
  const float* Wk   = (const float*)d_in[5];
  const float* Wv   = (const float*)d_in[6];
  const float* Wo   = (const float*)d_in[7];
  const float* Wg   = (const float*)d_in[8];
  float* out = (float*)d_out;

  char* ws = (char*)d_ws;
  short* xb   = (short*)(ws);                       // 4096x1024 bf16
  short* WbT  = (short*)(ws + 8388608);             // 1536x1024 bf16
  short* WoT  = (short*)(ws + 11534336);            // 1024x1024 bf16
  short* qh   = (short*)(ws + 26214400);            // (B,NH,T,HD) bf16 (q pre-scaled)
  short* kh   = (short*)(ws + 34603008);            // (B,NKV,T,HD)
  short* vhT  = (short*)(ws + 36700160);            // (B,NKV,HD,T)
  short* yb   = (short*)(ws + 38797312);            // 4096x1024 bf16

  k_prep<<<4608, 256, 0, stream>>>(x, Wq, Wk, Wv, Wo, xb, WbT, WoT);

  k_gemm_qkv<<<768, 256, 0, stream>>>(xb, WbT, x, ve, cosp, sinp, Wg, qh, kh, vhT);

  k_attn<<<1024, 256, 0, stream>>>(qh, kh, vhT, yb);

  k_gemm_bt<1024, true><<<512, 256, 0, stream>>>(yb, WoT, out, 1024);
}

// Round 19
// 83.099 us; speedup vs baseline: 1.0281x; 1.0281x over previous
//
#include <hip/hip_runtime.h>
#include <hip/hip_bf16.h>
#include <string.h>

typedef __attribute__((ext_vector_type(8))) short bf16x8;
typedef __attribute__((ext_vector_type(4))) short bf16x4;
typedef __attribute__((ext_vector_type(4))) float f32x4;
typedef __attribute__((ext_vector_type(4))) int i32x4;
typedef __attribute__((ext_vector_type(2))) int i32x2;

#define DEV __device__ __forceinline__
#define WIN_ 1024

DEV short f2bf(float f) {
  __hip_bfloat16 h = __float2bfloat16(f);
  short s; __builtin_memcpy(&s, &h, 2); return s;
}
DEV float bf2f(short s) {
  union { unsigned u; float f; } a; a.u = ((unsigned)(unsigned short)s) << 16;
  return a.f;
}
DEV unsigned pkbf2(float a, float b) {     // packed f32x2 -> bf16x2 (RNE), compiler-emitted
  __hip_bfloat162 h = __float22bfloat162_rn(make_float2(a, b));
  unsigned u; __builtin_memcpy(&u, &h, 4); return u;
}
DEV float fexp2(float x) {
#if __has_builtin(__builtin_amdgcn_exp2f)
  return __builtin_amdgcn_exp2f(x);
#else
  return exp2f(x);
#endif
}

DEV f32x4 mfma16(bf16x4 a, bf16x4 b, f32x4 c) {
#if __has_builtin(__builtin_amdgcn_mfma_f32_16x16x16bf16_1k)
  return __builtin_amdgcn_mfma_f32_16x16x16bf16_1k(a, b, c, 0, 0, 0);
#else
  asm volatile("s_nop 1\n\tv_mfma_f32_16x16x16_bf16 %0, %1, %2, %0\n\ts_nop 7\n\ts_nop 7"
               : "+v"(c) : "v"(a), "v"(b));
  return c;
#endif
}

DEV void gload16(const short* g, short* l) {
  __builtin_amdgcn_global_load_lds((const __attribute__((address_space(1))) unsigned int*)g,
                                   (__attribute__((address_space(3))) unsigned int*)l,
                                   16, 0, 0);
}

// ---------- fused prep: x->bf16 cast (8 floats/thread) + 4 weight transposes ----------
__global__ __launch_bounds__(256) void k_prep(const float* __restrict__ x,
    const float* __restrict__ Wq, const float* __restrict__ Wk, const float* __restrict__ Wv,
    const float* __restrict__ Wo, short* __restrict__ xb, short* __restrict__ WbT,
    short* __restrict__ WoT) {
  const int bid = blockIdx.x;
  if (bid < 2048) {                       // cvt: 4096x1024 f32 -> bf16, 8 elems/thread
    size_t i = ((size_t)bid * 256 + threadIdx.x) * 8;
    f32x4 v0 = *(const f32x4*)(x + i);
    f32x4 v1 = *(const f32x4*)(x + i + 4);
    i32x4 o = {(int)pkbf2(v0[0], v0[1]), (int)pkbf2(v0[2], v0[3]),
               (int)pkbf2(v1[0], v1[1]), (int)pkbf2(v1[2], v1[3])};
    *(i32x4*)(xb + i) = o;
    return;
  }
  int t = bid - 2048;
  const float* src; short* dst; int srcld, bx, by;
  if (t < 1024)      { src = Wq; dst = WbT;                        srcld = 1024; bx = t & 31;          by = t >> 5; }
  else if (t < 1280) { src = Wk; dst = WbT + (size_t)1024 * 1024;  srcld = 256;  bx = (t - 1024) & 7;  by = (t - 1024) >> 3; }
  else if (t < 1536) { src = Wv; dst = WbT + (size_t)1280 * 1024;  srcld = 256;  bx = (t - 1280) & 7;  by = (t - 1280) >> 3; }
  else               { src = Wo; dst = WoT;                        srcld = 1024; bx = (t - 1536) & 31; by = (t - 1536) >> 5; }
  __shared__ float tile[32][33];
  const int n0 = bx * 32, k0 = by * 32;
  const int tx = threadIdx.x & 31, ty = threadIdx.x >> 5;
#pragma unroll
  for (int i = 0; i < 4; ++i)
    tile[ty * 4 + i][tx] = src[(size_t)(k0 + ty * 4 + i) * srcld + n0 + tx];
  __syncthreads();
#pragma unroll
  for (int i = 0; i < 4; ++i)
    dst[(size_t)(n0 + ty * 4 + i) * 1024 + k0 + tx] = f2bf(tile[tx][ty * 4 + i]);
}

// ======== fused QKV GEMM + RoPE/RMSNorm/gate epilogue ========
// 1D grid (768), XCD-swizzled decode (T1).
__global__ __launch_bounds__(256) void k_gemm_qkv(const short* __restrict__ A, const short* __restrict__ BT,
    const float* __restrict__ x, const float* __restrict__ ve,
    const float* __restrict__ cosp, const float* __restrict__ sinp, const float* __restrict__ Wg,
    short* __restrict__ qh, short* __restrict__ kh, short* __restrict__ vhT) {
  const int K = 1024;
  __shared__ short As[2][8192];   // 128 rows x 64
  __shared__ short Bs[2][4096];   // 64 rows x 64
  const int tid = threadIdx.x;
  const int l = tid & 63, w = tid >> 6;
  const int l15 = l & 15, hi = l >> 4;
  const int bid = blockIdx.x;
  const int wg = (bid & 7) * 96 + (bid >> 3);       // XCD-contiguous remap (768 = 8*96)
  const int bx = wg % 24;
  const int m0 = (wg / 24) * 128, n0 = bx * 64;
  const int srow = tid >> 3;
  const int segsw = 8 * ((tid & 7) ^ (srow & 7));
  const int lo = tid * 8;
  const short* pa = A + (size_t)(m0 + srow) * K + segsw;
  const short* pb = BT + (size_t)(n0 + srow) * K + segsw;
  const int f8 = l15 & 7;

  f32x4 acc[2][4];
#pragma unroll
  for (int i = 0; i < 2; ++i)
#pragma unroll
    for (int j = 0; j < 4; ++j) acc[i][j] = (f32x4){0.f, 0.f, 0.f, 0.f};

  auto stage = [&](int buf, int koff) {
    gload16(pa + koff,          &As[buf][lo]);
    gload16(pa + 32 * K + koff, &As[buf][lo + 2048]);
    gload16(pa + 64 * K + koff, &As[buf][lo + 4096]);
    gload16(pa + 96 * K + koff, &As[buf][lo + 6144]);
    gload16(pb + koff,          &Bs[buf][lo]);
    gload16(pb + 32 * K + koff, &Bs[buf][lo + 2048]);
  };

  stage(0, 0);
  __syncthreads();
  int cur = 0;
  for (int k0 = 0; k0 < K; k0 += 64) {
    if (k0 + 64 < K) stage(cur ^ 1, k0 + 64);
    bf16x8 af[2][2], bfr[4][2];
#pragma unroll
    for (int c = 0; c < 2; ++c) {
      int seg = 8 * ((4 * c + hi) ^ f8);
#pragma unroll
      for (int mi = 0; mi < 2; ++mi)
        af[mi][c] = *(const bf16x8*)&As[cur][(32 * w + 16 * mi + l15) * 64 + seg];
#pragma unroll
      for (int ni = 0; ni < 4; ++ni)
        bfr[ni][c] = *(const bf16x8*)&Bs[cur][(16 * ni + l15) * 64 + seg];
    }
#pragma unroll
    for (int c = 0; c < 2; ++c)
#pragma unroll
      for (int mi = 0; mi < 2; ++mi)
#pragma unroll
        for (int ni = 0; ni < 4; ++ni)
          acc[mi][ni] = __builtin_amdgcn_mfma_f32_16x16x32_bf16(af[mi][c], bfr[ni][c], acc[mi][ni], 0, 0, 0);
    __syncthreads();
    cur ^= 1;
  }

  // ---------------- fused epilogue ----------------
  if (bx < 20) {
    short* dst0 = (bx < 16) ? qh : kh;
#pragma unroll
    for (int mi = 0; mi < 2; ++mi)
#pragma unroll
      for (int r = 0; r < 4; ++r) {
        int bt = m0 + 32 * w + 16 * mi + 4 * hi + r;
        int b = bt >> 11, t = bt & 2047;
        float c0 = cosp[bt * 32 + l15],      s0 = sinp[bt * 32 + l15];
        float c1 = cosp[bt * 32 + 16 + l15], s1 = sinp[bt * 32 + 16 + l15];
        float a0 = acc[mi][0][r], b0 = acc[mi][2][r];
        float a1 = acc[mi][1][r], b1 = acc[mi][3][r];
        float o0 = a0 * c0 + b0 * s0;
        float o2 = b0 * c0 - a0 * s0;
        float o1 = a1 * c1 + b1 * s1;
        float o3 = b1 * c1 - a1 * s1;
        float ss = o0 * o0 + o1 * o1 + o2 * o2 + o3 * o3;
        ss += __shfl_xor(ss, 1); ss += __shfl_xor(ss, 2);
        ss += __shfl_xor(ss, 4); ss += __shfl_xor(ss, 8);
        float rinv = rsqrtf(ss * (1.f / 64.f) + 1e-6f);
        if (bx < 16) rinv *= 0.18033688011112042f;   // 0.125 * log2(e)
        size_t rb = ((size_t)((b * ((bx < 16) ? 16 : 4) + ((bx < 16) ? bx : bx - 16)) * 2048 + t)) * 64;
        dst0[rb + l15]      = f2bf(o0 * rinv);
        dst0[rb + 16 + l15] = f2bf(o1 * rinv);
        dst0[rb + 32 + l15] = f2bf(o2 * rinv);
        dst0[rb + 48 + l15] = f2bf(o3 * rinv);
      }
  } else {
    const int kvh = bx - 20;
#pragma unroll
    for (int mi = 0; mi < 2; ++mi)
#pragma unroll
      for (int r = 0; r < 4; ++r) {
        int bt = m0 + 32 * w + 16 * mi + 4 * hi + r;
        int b = bt >> 11, t = bt & 2047;
        const float* xr = x + (size_t)bt * 1024;
        float z = 0.f;
#pragma unroll
        for (int gg = 0; gg < 32; ++gg) z += xr[gg] * Wg[gg * 4 + kvh];
        float gate = 2.f / (1.f + __expf(-z));
        const float* vep = ve + (size_t)bt * 256 + kvh * 64;
        short* dst = vhT + (size_t)(b * 4 + kvh) * 131072 + t;
#pragma unroll
        for (int ni = 0; ni < 4; ++ni) {
          int d = 16 * ni + l15;
          float vv = acc[mi][ni][r] + gate * vep[d];
          dst[(size_t)d * 2048] = f2bf(vv);
        }
      }
  }
}

// ---------------- bf16 GEMM: C = A(MxK) * BT(NxK)^T ---------------- (gemm2)
// 1D grid (512), XCD-swizzled decode (T1).
template <int LDC, bool F32OUT>
__global__ __launch_bounds__(256) void k_gemm_bt(const short* __restrict__ A, const short* __restrict__ BT,
                                                 void* __restrict__ Cv, int K) {
  __shared__ short As[2][8192];
  __shared__ short Bs[2][4096];
  const int tid = threadIdx.x;
  const int l = tid & 63, w = tid >> 6;
  const int l15 = l & 15, hi = l >> 4;
  const int bid = blockIdx.x;
  const int wg = (bid & 7) * 64 + (bid >> 3);       // XCD-contiguous remap (512 = 8*64)
  const int m0 = (wg >> 4) * 128, n0 = (wg & 15) * 64;
  const int srow = tid >> 3;
  const int segsw = 8 * ((tid & 7) ^ (srow & 7));
  const int lo = tid * 8;
  const short* pa = A + (size_t)(m0 + srow) * K + segsw;
  const short* pb = BT + (size_t)(n0 + srow) * K + segsw;
  const int f8 = l15 & 7;

  f32x4 acc[2][4];
#pragma unroll
  for (int i = 0; i < 2; ++i)
#pragma unroll
    for (int j = 0; j < 4; ++j) acc[i][j] = (f32x4){0.f, 0.f, 0.f, 0.f};

  auto stage = [&](int buf, int koff) {
    gload16(pa + koff,          &As[buf][lo]);
    gload16(pa + 32 * K + koff, &As[buf][lo + 2048]);
    gload16(pa + 64 * K + koff, &As[buf][lo + 4096]);
    gload16(pa + 96 * K + koff, &As[buf][lo + 6144]);
    gload16(pb + koff,          &Bs[buf][lo]);
    gload16(pb + 32 * K + koff, &Bs[buf][lo + 2048]);
  };

  stage(0, 0);
  __syncthreads();
  int cur = 0;
  for (int k0 = 0; k0 < K; k0 += 64) {
    if (k0 + 64 < K) stage(cur ^ 1, k0 + 64);
    bf16x8 af[2][2], bfr[4][2];
#pragma unroll
    for (int c = 0; c < 2; ++c) {
      int seg = 8 * ((4 * c + hi) ^ f8);
#pragma unroll
      for (int mi = 0; mi < 2; ++mi)
        af[mi][c] = *(const bf16x8*)&As[cur][(32 * w + 16 * mi + l15) * 64 + seg];
#pragma unroll
      for (int ni = 0; ni < 4; ++ni)
        bfr[ni][c] = *(const bf16x8*)&Bs[cur][(16 * ni + l15) * 64 + seg];
    }
#pragma unroll
    for (int c = 0; c < 2; ++c)
#pragma unroll
      for (int mi = 0; mi < 2; ++mi)
#pragma unroll
        for (int ni = 0; ni < 4; ++ni)
          acc[mi][ni] = __builtin_amdgcn_mfma_f32_16x16x32_bf16(af[mi][c], bfr[ni][c], acc[mi][ni], 0, 0, 0);
    __syncthreads();
    cur ^= 1;
  }
#pragma unroll
  for (int mi = 0; mi < 2; ++mi)
#pragma unroll
    for (int ni = 0; ni < 4; ++ni)
#pragma unroll
      for (int r = 0; r < 4; ++r) {
        int crow = m0 + 32 * w + 16 * mi + 4 * hi + r;
        int ccol = n0 + 16 * ni + l15;
        if (F32OUT) ((float*)Cv)[(size_t)crow * LDC + ccol] = acc[mi][ni][r];
        else        ((short*)Cv)[(size_t)crow * LDC + ccol] = f2bf(acc[mi][ni][r]);
      }
}

// ---------------- flash attention, sliding-window causal, GQA ----------------
// r16 proven best: 4 waves x 16 q-rows, 256 threads, 1024-block balanced grid,
// x2-unrolled even/odd LDS buffers, static-max softmax (P = exp2(s), bound
// s <= 11.54 from rmsnorm), lsum via ones-MFMA, setprio around compute.
__global__ __launch_bounds__(256) void k_attn(const short* __restrict__ qh, const short* __restrict__ kh,
                                              const short* __restrict__ vhT, short* __restrict__ yb) {
  __shared__ i32x4 lds4[2][1024];   // [buf][ K 8KB | V 8KB ]
  char* base = (char*)lds4;
  const int bid = blockIdx.x;
  const int kq = bid >> 8, low = bid & 255;
  const int h = low & 15, b = (low >> 4) & 1, q0 = low >> 5;
  const int qt = (kq == 0) ? (31 - q0) : (kq == 1) ? (16 + q0) : (kq == 2) ? (15 - q0) : q0;
  const int kvh = h >> 2;
  const int qs = qt * 64;
  const int tid = threadIdx.x;
  const int w = tid >> 6, l = tid & 63, l15 = l & 15, hi = l >> 4;
  const int qi = qs + 16 * w + l15;          // this lane's softmax row
  const int rsw = (l15 & 7) << 4;

  const short* qb = qh + ((size_t)((b * 16 + h) * 2048 + qs + 16 * w + l15)) * 64;
  bf16x8 qf0 = *(const bf16x8*)(qb + 8 * hi);
  bf16x8 qf1 = *(const bf16x8*)(qb + 32 + 8 * hi);

  f32x4 oacc[4];
#pragma unroll
  for (int i = 0; i < 4; ++i) oacc[i] = (f32x4){0.f, 0.f, 0.f, 0.f};
  f32x4 lsacc = (f32x4){0.f, 0.f, 0.f, 0.f};
  const bf16x4 vone = {(short)0x3F80, (short)0x3F80, (short)0x3F80, (short)0x3F80};

  const int kt_lo = (qs >= 1024) ? ((qs - 1024) >> 6) : 0;
  const int kt_hi = qs >> 6;
  const short* kbase = kh + ((size_t)(b * 4 + kvh) * 2048) * 64;
  const short* vbase = vhT + ((size_t)(b * 4 + kvh) * 64) * 2048;

  const int srow = tid >> 3, sseg = tid & 7;
  const int swz = (srow & 7) << 4;
  const int ko = ((srow << 7) + (sseg << 4)) ^ swz;
  const short* kp = kbase + (size_t)(kt_lo * 64 + srow) * 64 + sseg * 8;
  const short* vp = vbase + (size_t)srow * 2048 + kt_lo * 64 + sseg * 8;
  i32x4 rk0, rk1, rv0, rv1;

#define LOADT() do { \
    rk0 = *(const i32x4*)kp; \
    rk1 = *(const i32x4*)(kp + 2048); \
    rv0 = *(const i32x4*)vp; \
    rv1 = *(const i32x4*)(vp + 32 * 2048); \
  } while (0)

#define WRITET(DST) do { \
    char* kd = (DST); \
    *(i32x4*)(kd + ko) = rk0; \
    *(i32x4*)(kd + ko + 4096) = rk1; \
    char* vd = kd + 8192; \
    *(i32x4*)(vd + ko) = rv0; \
    *(i32x4*)(vd + ko + 4096) = rv1; \
  } while (0)

  // one full tile: QK^T -> mask(edge) -> exp2 -> pack -> lsum-MFMA -> PV
  auto TILE = [&](char* kbuf, int kt) {
    char* vbuf = kbuf + 8192;
    f32x4 s[4];
#pragma unroll
    for (int nt = 0; nt < 4; ++nt) s[nt] = (f32x4){0.f, 0.f, 0.f, 0.f};
#pragma unroll
    for (int c = 0; c < 2; ++c) {
      bf16x8 qc = c ? qf1 : qf0;
#pragma unroll
      for (int nt = 0; nt < 4; ++nt) {
        bf16x8 kf = *(const bf16x8*)(kbuf + ((((16 * nt + l15) << 7) + (c << 6) + (hi << 4)) ^ rsw));
        s[nt] = __builtin_amdgcn_mfma_f32_16x16x32_bf16(kf, qc, s[nt], 0, 0, 0);
      }
    }
    if (kt == kt_lo || kt == kt_hi) {
      const int k0 = kt * 64;
#pragma unroll
      for (int nt = 0; nt < 4; ++nt)
#pragma unroll
        for (int r = 0; r < 4; ++r) {
          int kj = k0 + 16 * nt + 4 * hi + r;
          if (kj > qi || (qi - kj) > WIN_) s[nt][r] = -1e30f;
        }
    }
    // P = exp2(s) (static max: s <= 11.54 from rmsnorm bound; masked -> 0)
#pragma unroll
    for (int nt = 0; nt < 4; ++nt)
#pragma unroll
      for (int r = 0; r < 4; ++r) s[nt][r] = fexp2(s[nt][r]);

    bf16x4 pa[4];
#pragma unroll
    for (int nt = 0; nt < 4; ++nt) {
      i32x2 pk = {(int)pkbf2(s[nt][0], s[nt][1]), (int)pkbf2(s[nt][2], s[nt][3])};
      pa[nt] = __builtin_bit_cast(bf16x4, pk);
    }
    // lsum on the MFMA pipe: D[.][q=l15] += sum_k 1 * P[k][q]
#pragma unroll
    for (int nt = 0; nt < 4; ++nt) lsacc = mfma16(vone, pa[nt], lsacc);
#pragma unroll
    for (int dt = 0; dt < 4; ++dt) {
      int rowb = ((16 * dt + l15) << 7) + (hi << 3);
#pragma unroll
      for (int nt = 0; nt < 4; ++nt) {
        i32x2 vv = *(const i32x2*)(vbuf + ((rowb + 32 * nt) ^ rsw));
        oacc[dt] = mfma16(__builtin_bit_cast(bf16x4, vv), pa[nt], oacc[dt]);
      }
    }
  };

  LOADT();
  WRITET(base);
  __syncthreads();

  int kt = kt_lo;
  for (;;) {
    // even tile: compute from buf0, prefetch -> buf1
    if (kt < kt_hi) { kp += 4096; vp += 64; LOADT(); }
    __builtin_amdgcn_s_setprio(1);
    TILE(base, kt);
    __builtin_amdgcn_s_setprio(0);
    if (kt < kt_hi) WRITET(base + 16384);
    __syncthreads();
    if (kt == kt_hi) break;
    ++kt;
    // odd tile: compute from buf1, prefetch -> buf0
    if (kt < kt_hi) { kp += 4096; vp += 64; LOADT(); }
    __builtin_amdgcn_s_setprio(1);
    TILE(base + 16384, kt);
    __builtin_amdgcn_s_setprio(0);
    if (kt < kt_hi) WRITET(base);
    __syncthreads();
    if (kt == kt_hi) break;
    ++kt;
  }
#undef LOADT
#undef WRITET

  // ---- epilogue: lsum already summed across all k by the ones-MFMA ----
  float inv = 1.f / lsacc[0];
  size_t orow = (size_t)(b * 2048 + qs + 16 * w + l15);
#pragma unroll
  for (int dt = 0; dt < 4; ++dt) {
    int col0 = h * 64 + 16 * dt + 4 * hi;
    i32x2 pk = {(int)pkbf2(oacc[dt][0] * inv, oacc[dt][1] * inv),
                (int)pkbf2(oacc[dt][2] * inv, oacc[dt][3] * inv)};
    *(i32x2*)(yb + orow * 1024 + col0) = pk;
  }
}

extern "C" void kernel_launch(void* const* d_in, const int* in_sizes, int n_in,
                              void* d_out, int out_size, void* d_ws, size_t ws_size,
                              hipStream_t stream) {
  const float* x    = (const float*)d_in[0];
  const float* ve   = (const float*)d_in[1];
  const float* cosp = (const float*)d_in[2];
  const float* sinp = (const float*)d_in[3];
  const float* Wq   = (const float*)d_in[4];
  const float* Wk   = (const float*)d_in[5];
  const float* Wv   = (const float*)d_in[6];
  const float* Wo   = (const float*)d_in[7];
  const float* Wg   = (const float*)d_in[8];
  float* out = (float*)d_out;

  char* ws = (char*)d_ws;
  short* xb   = (short*)(ws);                       // 4096x1024 bf16
  short* WbT  = (short*)(ws + 8388608);             // 1536x1024 bf16
  short* WoT  = (short*)(ws + 11534336);            // 1024x1024 bf16
  short* qh   = (short*)(ws + 26214400);            // (B,NH,T,HD) bf16 (q pre-scaled)
  short* kh   = (short*)(ws + 34603008);            // (B,NKV,T,HD)
  short* vhT  = (short*)(ws + 36700160);            // (B,NKV,HD,T)
  short* yb   = (short*)(ws + 38797312);            // 4096x1024 bf16

  k_prep<<<4608, 256, 0, stream>>>(x, Wq, Wk, Wv, Wo, xb, WbT, WoT);

  k_gemm_qkv<<<768, 256, 0, stream>>>(xb, WbT, x, ve, cosp, sinp, Wg, qh, kh, vhT);

  k_attn<<<1024, 256, 0, stream>>>(qh, kh, vhT, yb);

  k_gemm_bt<1024, true><<<512, 256, 0, stream>>>(yb, WoT, out, 1024);
}